// Round 13
// baseline (18.541 us; speedup 1.0000x reference)
//
#include <hip/hip_runtime.h>

// SVR: out[i] = sum_j exp(-|f_i-f_j|^2/50)*alpha[j] + bias.  N=4096, D=64.
// Round 13: single-pass fused main (no prep dispatch, no Ft round-trip).
//  - block = 256 i-rows (4 waves x 4 i-tiles) x 128 j-rows (blockIdx.y of 32)
//  - stage own j-rows fp32->bf16(LDS, frag order), shared by 4 waves
//    (R8's mistake was 64x redundant conversion; here it's 16x on 1MB = cheap)
//  - ajl[j] = alpha_j * exp2(-sj2) computed during staging
//  - B-frags converted in-register; si2 via shfl_xor(16,32) over kg groups
//  - partials ws[p][i] plain stores (exactly-once, no init), reduce adds bias
// exp2 identity: exp(-(si+sj-2dot)/50) = exp2(K1*dot)*exp2(-si2)*exp2(-sj2);
// data scaled by sqrt(K1) so MFMA emits K1*dot directly.
// Frag map (16x16x32 bf16): lane l of tile t, half h: row=16*t+(l&15),
// k=32*h+(l>>4)*8..+7 -> chunk (t*2+h)*64+l.  A/B share lane->k map.
// C/D: col=lane&15 (i), row=(lane>>4)*4+reg (j)  [verified m89; R4-R12 passed]

#define NN 4096
#define DD 64
#define NPJ 32                 // j-chunks; 128 j-rows = 8 tiles each
#define JROWS 128
#define NTL 8                  // j-tiles per block

typedef __attribute__((ext_vector_type(8))) short bf16x8;
typedef __attribute__((ext_vector_type(4))) float f32x4;

#define C2 0.028853901f        // log2(e)/50
#define SQK 0.2402244f         // sqrt(2*log2(e)/50)

static __device__ __forceinline__ unsigned short f2bf(float f) {
    unsigned int x = __float_as_uint(f);
    x += 0x7fffu + ((x >> 16) & 1u);          // RNE
    return (unsigned short)(x >> 16);
}

static __device__ __forceinline__ bf16x8 pack8(float4 a, float4 b) {
    bf16x8 u;
    u[0] = (short)f2bf(a.x * SQK); u[1] = (short)f2bf(a.y * SQK);
    u[2] = (short)f2bf(a.z * SQK); u[3] = (short)f2bf(a.w * SQK);
    u[4] = (short)f2bf(b.x * SQK); u[5] = (short)f2bf(b.y * SQK);
    u[6] = (short)f2bf(b.z * SQK); u[7] = (short)f2bf(b.w * SQK);
    return u;
}

// ---------- fused main: stage j->LDS, convert B in-reg, MFMA+exp2, store partial ----------
__global__ __launch_bounds__(256) void svr_fused(const float* __restrict__ F,
                                                 const float* __restrict__ alpha,
                                                 float* __restrict__ ws) {
    __shared__ bf16x8 jf[NTL * 2 * 64];                 // 16 KB frag-order j-tiles
    __shared__ __align__(16) float ajl[JROWS];          // alpha_j * exp2(-sj2)

    const int tid  = threadIdx.x;
    const int lane = tid & 63;
    const int wave = tid >> 6;
    const int jBase = blockIdx.y * JROWS;

    // ---- stage: thread t handles row r = t>>1, k-half h = t&1 (32 floats) ----
    {
        const int r = tid >> 1;
        const int h = tid & 1;
        const float4* src = reinterpret_cast<const float4*>(
            F + (size_t)(jBase + r) * DD + h * 32);
        float4 v[8];
#pragma unroll
        for (int q = 0; q < 8; ++q) v[q] = src[q];      // 128B contiguous, coalesced

        float p = 0.f;
#pragma unroll
        for (int q = 0; q < 8; ++q) {
            p = fmaf(v[q].x, v[q].x, p); p = fmaf(v[q].y, v[q].y, p);
            p = fmaf(v[q].z, v[q].z, p); p = fmaf(v[q].w, v[q].w, p);
        }
        p += __shfl_xor(p, 1);                          // join the two k-halves
        if (h == 0) ajl[r] = alpha[jBase + r] * exp2f(-p * C2);

        const int tl = r >> 4, rr = r & 15;
#pragma unroll
        for (int kgl = 0; kgl < 4; ++kgl)               // 4 chunks of this half
            jf[(tl * 2 + h) * 64 + kgl * 16 + rr] = pack8(v[2 * kgl], v[2 * kgl + 1]);
    }

    // ---- B-side: 4 i-tiles/wave converted in-register + exp2(-si2) scales ----
    const int ig    = blockIdx.x * 4 + wave;            // i-group 0..63 (64 rows)
    const int iBase = ig * 64;
    const int kg    = lane >> 4;
    const int c     = lane & 15;

    bf16x8 b0[4], b1[4];
    float  ei[4];
#pragma unroll
    for (int q = 0; q < 4; ++q) {
        const float4* fp = reinterpret_cast<const float4*>(
            F + (size_t)(iBase + q * 16 + c) * DD);
        const float4 g0 = fp[kg * 2],     g1 = fp[kg * 2 + 1];      // k: kg*8..+7
        const float4 g2 = fp[8 + kg * 2], g3 = fp[8 + kg * 2 + 1];  // k: 32+kg*8..
        b0[q] = pack8(g0, g1);
        b1[q] = pack8(g2, g3);
        float nq = 0.f;
        nq = fmaf(g0.x, g0.x, nq); nq = fmaf(g0.y, g0.y, nq);
        nq = fmaf(g0.z, g0.z, nq); nq = fmaf(g0.w, g0.w, nq);
        nq = fmaf(g1.x, g1.x, nq); nq = fmaf(g1.y, g1.y, nq);
        nq = fmaf(g1.z, g1.z, nq); nq = fmaf(g1.w, g1.w, nq);
        nq = fmaf(g2.x, g2.x, nq); nq = fmaf(g2.y, g2.y, nq);
        nq = fmaf(g2.z, g2.z, nq); nq = fmaf(g2.w, g2.w, nq);
        nq = fmaf(g3.x, g3.x, nq); nq = fmaf(g3.y, g3.y, nq);
        nq = fmaf(g3.z, g3.z, nq); nq = fmaf(g3.w, g3.w, nq);
        nq += __shfl_xor(nq, 16);
        nq += __shfl_xor(nq, 32);                       // sum over kg -> full |row|^2
        ei[q] = exp2f(-nq * C2);
    }

    __syncthreads();

    // ---- main loop: 8 j-tiles x 4 i-tiles ----
    f32x4 acc0 = {0.f,0.f,0.f,0.f}, acc1 = {0.f,0.f,0.f,0.f};
    f32x4 acc2 = {0.f,0.f,0.f,0.f}, acc3 = {0.f,0.f,0.f,0.f};

#pragma unroll
    for (int tl = 0; tl < NTL; ++tl) {
        const bf16x8 a0 = jf[(tl * 2 + 0) * 64 + lane];   // ds_read_b128, 2-way=free
        const bf16x8 a1 = jf[(tl * 2 + 1) * 64 + lane];
        const float4 aj = *reinterpret_cast<const float4*>(&ajl[tl * 16 + kg * 4]);
#define TILE(acc, bA, bB)                                                   \
        {                                                                   \
            f32x4 d0 = {0.f,0.f,0.f,0.f}, d1 = {0.f,0.f,0.f,0.f};           \
            d0 = __builtin_amdgcn_mfma_f32_16x16x32_bf16(a0, bA, d0, 0,0,0);\
            d1 = __builtin_amdgcn_mfma_f32_16x16x32_bf16(a1, bB, d1, 0,0,0);\
            acc.x = fmaf(exp2f(d0[0] + d1[0]), aj.x, acc.x);                \
            acc.y = fmaf(exp2f(d0[1] + d1[1]), aj.y, acc.y);                \
            acc.z = fmaf(exp2f(d0[2] + d1[2]), aj.z, acc.z);                \
            acc.w = fmaf(exp2f(d0[3] + d1[3]), aj.w, acc.w);                \
        }
        TILE(acc0, b0[0], b1[0])
        TILE(acc1, b0[1], b1[1])
        TILE(acc2, b0[2], b1[2])
        TILE(acc3, b0[3], b1[3])
#undef TILE
    }

    float s0 = (acc0.x + acc0.y) + (acc0.z + acc0.w);
    float s1 = (acc1.x + acc1.y) + (acc1.z + acc1.w);
    float s2 = (acc2.x + acc2.y) + (acc2.z + acc2.w);
    float s3 = (acc3.x + acc3.y) + (acc3.z + acc3.w);
    s0 += __shfl_xor(s0, 16); s0 += __shfl_xor(s0, 32);
    s1 += __shfl_xor(s1, 16); s1 += __shfl_xor(s1, 32);
    s2 += __shfl_xor(s2, 16); s2 += __shfl_xor(s2, 32);
    s3 += __shfl_xor(s3, 16); s3 += __shfl_xor(s3, 32);
    if (lane < 16) {                                    // partial, exactly once
        float* w = ws + (size_t)blockIdx.y * NN + iBase + lane;
        w[0]  = s0 * ei[0];
        w[16] = s1 * ei[1];
        w[32] = s2 * ei[2];
        w[48] = s3 * ei[3];
    }
}

// ---------- reduce: out[i] = bias + sum_{p<32} ws[p][i] ----------
__global__ __launch_bounds__(256) void svr_reduce(const float* __restrict__ ws,
                                                  const float* __restrict__ bias,
                                                  float* __restrict__ out) {
    const int i = blockIdx.x * 256 + threadIdx.x;
    float s = bias[0];
#pragma unroll
    for (int p = 0; p < NPJ; ++p) s += ws[(size_t)p * NN + i];
    out[i] = s;
}

// ---------------- launch ----------------
extern "C" void kernel_launch(void* const* d_in, const int* in_sizes, int n_in,
                              void* d_out, int out_size, void* d_ws, size_t ws_size,
                              hipStream_t stream) {
    const float* F     = (const float*)d_in[0];
    const float* alpha = (const float*)d_in[1];
    const float* bias  = (const float*)d_in[2];
    float* out = (float*)d_out;
    float* ws  = (float*)d_ws;                          // 512 KB partials

    svr_fused<<<dim3(16, NPJ), dim3(256), 0, stream>>>(F, alpha, ws);
    svr_reduce<<<dim3(NN / 256), dim3(256), 0, stream>>>(ws, bias, out);
}

// Round 14
// 15.841 us; speedup vs baseline: 1.1705x; 1.1705x over previous
//
#include <hip/hip_runtime.h>

// SVR: out[i] = sum_j exp(-|f_i-f_j|^2/50)*alpha[j] + bias.  N=4096, D=64.
// Round 14 = R11 (best, 17.8us) + epilogue instruction-count cuts:
//  1. exp2f (OCML precise, multi-instr fixup) -> raw v_exp_f32 via
//     __builtin_amdgcn_exp2f. 16.7M calls; each saved instr ~= 0.22us.
//  2. chained MFMA d=mfma(a1,b,mfma(a0,b,0)) removes the d0+d1 VALU add
//     per element (4 independent i-tiles keep the MFMA pipe fed).
// Structure unchanged: prep (retile fp32->bf16*sqrt(K1) frag-order Ft, norms,
// ajp=alpha*exp2(-sj2), out=bias) + mfma4 (4 i-tiles/wave, NPY=32, atomics).
//
// Frag map (16x16x32 bf16): lane l of tile t, half h: row=16*t+(l&15),
// k=32*h+(l>>4)*8..+7 -> chunk (t*2+h)*64+l.  A/B share lane->k map.
// C/D: col=lane&15 (i), row=(lane>>4)*4+reg (j)  [verified m89; R4-R13 passed]

#define NN 4096
#define DD 64
#define NPY 32                 // j-chunks; 8 j-tiles (256 j-rows) each
#define NT (NN / 16)           // 256 row-tiles

typedef __attribute__((ext_vector_type(8))) short bf16x8;
typedef __attribute__((ext_vector_type(8))) unsigned short u16x8;
typedef __attribute__((ext_vector_type(4))) float f32x4;

#define C2 0.028853901f        // log2(e)/50
#define SQK 0.2402244f         // sqrt(2*log2(e)/50)

static __device__ __forceinline__ float fexp2(float x) {   // raw v_exp_f32 (2^x)
#if __has_builtin(__builtin_amdgcn_exp2f)
    return __builtin_amdgcn_exp2f(x);
#else
    float r;
    asm("v_exp_f32 %0, %1" : "=v"(r) : "v"(x));
    return r;
#endif
}

static __device__ __forceinline__ unsigned short f2bf(float f) {
    unsigned int x = __float_as_uint(f);
    x += 0x7fffu + ((x >> 16) & 1u);          // RNE
    return (unsigned short)(x >> 16);
}

// ---------- prep: retile+convert (scaled), norms, ajp, out=bias ----------
__global__ __launch_bounds__(256) void svr_prep(const float* __restrict__ F,
                                                const float* __restrict__ alpha,
                                                const float* __restrict__ bias,
                                                u16x8* __restrict__ Ft,
                                                float* __restrict__ sq2,
                                                float* __restrict__ ajp,
                                                float* __restrict__ out) {
    __shared__ float part[256];
    const int tid = threadIdx.x;
    const int g = blockIdx.x * 256 + tid;           // 0..32767
    const int l = g & 63;
    const int h = (g >> 6) & 1;
    const int t = g >> 7;
    const int row = t * 16 + (l & 15);
    const int k0  = h * 32 + (l >> 4) * 8;

    const float4* src = reinterpret_cast<const float4*>(F + (size_t)row * DD + k0);
    const float4 v0 = src[0];
    const float4 v1 = src[1];
    u16x8 u;                                        // scaled by sqrt(K1)
    u[0] = f2bf(v0.x * SQK); u[1] = f2bf(v0.y * SQK);
    u[2] = f2bf(v0.z * SQK); u[3] = f2bf(v0.w * SQK);
    u[4] = f2bf(v1.x * SQK); u[5] = f2bf(v1.y * SQK);
    u[6] = f2bf(v1.z * SQK); u[7] = f2bf(v1.w * SQK);
    Ft[g] = u;

    float p = v0.x * v0.x;                          // unscaled norms
    p = fmaf(v0.y, v0.y, p); p = fmaf(v0.z, v0.z, p); p = fmaf(v0.w, v0.w, p);
    p = fmaf(v1.x, v1.x, p); p = fmaf(v1.y, v1.y, p); p = fmaf(v1.z, v1.z, p);
    p = fmaf(v1.w, v1.w, p);
    part[tid] = p;
    __syncthreads();
    if ((tid & 112) == 0) {    // one thread per row: tid in {0..15, 128..143}
        float s = part[tid]      + part[tid + 16] + part[tid + 32] + part[tid + 48]
                + part[tid + 64] + part[tid + 80] + part[tid + 96] + part[tid + 112];
        const float w = s * C2;                     // si2 = |f|^2 * log2(e)/50
        sq2[row] = w;
        ajp[row] = alpha[row] * fexp2(-w);          // alpha_j * exp2(-sj2)
    }
    if (g < NN) out[g] = bias[0];                   // re-init every call
}

// ---------- main: 4 i-tiles/wave, chained MFMA, raw exp2 ----------
__global__ __launch_bounds__(256) void svr_mfma4(const bf16x8* __restrict__ Ft,
                                                 const float* __restrict__ ajp,
                                                 const float* __restrict__ sq2,
                                                 float* __restrict__ out) {
    const int lane = threadIdx.x & 63;
    const int wave = threadIdx.x >> 6;
    const int ig   = blockIdx.x * 4 + wave;          // i-group 0..63 (64 rows)
    const int it0  = ig * 4;
    const int iBase = it0 * 16;
    const int p    = blockIdx.y;                     // 0..31
    const int jt0  = p * (NT / NPY);                 // 8 j-tiles
    const int kg   = lane >> 4;
    const int c    = lane & 15;

    // B-frags for 4 i-tiles (32 VGPR, resident) + i-side exp scales
    const bf16x8 b00 = Ft[(it0 + 0) * 128 + lane], b01 = Ft[(it0 + 0) * 128 + 64 + lane];
    const bf16x8 b10 = Ft[(it0 + 1) * 128 + lane], b11 = Ft[(it0 + 1) * 128 + 64 + lane];
    const bf16x8 b20 = Ft[(it0 + 2) * 128 + lane], b21 = Ft[(it0 + 2) * 128 + 64 + lane];
    const bf16x8 b30 = Ft[(it0 + 3) * 128 + lane], b31 = Ft[(it0 + 3) * 128 + 64 + lane];
    const float e0 = fexp2(-sq2[iBase + c]);
    const float e1 = fexp2(-sq2[iBase + 16 + c]);
    const float e2 = fexp2(-sq2[iBase + 32 + c]);
    const float e3 = fexp2(-sq2[iBase + 48 + c]);

    const float4* alv = reinterpret_cast<const float4*>(ajp);

    f32x4 acc0 = {0.f,0.f,0.f,0.f}, acc1 = {0.f,0.f,0.f,0.f};
    f32x4 acc2 = {0.f,0.f,0.f,0.f}, acc3 = {0.f,0.f,0.f,0.f};

#pragma unroll
    for (int k = 0; k < NT / NPY; ++k) {
        const int jt = jt0 + k;
        const bf16x8 a0 = Ft[jt * 128 + lane];       // 1KB coalesced loads
        const bf16x8 a1 = Ft[jt * 128 + 64 + lane];
        const float4 aj = alv[jt * 4 + kg];
#define TILE(acc, bA, bB)                                                   \
        {                                                                   \
            f32x4 d = {0.f,0.f,0.f,0.f};                                    \
            d = __builtin_amdgcn_mfma_f32_16x16x32_bf16(a0, bA, d, 0,0,0);  \
            d = __builtin_amdgcn_mfma_f32_16x16x32_bf16(a1, bB, d, 0,0,0);  \
            acc.x = fmaf(fexp2(d[0]), aj.x, acc.x);                         \
            acc.y = fmaf(fexp2(d[1]), aj.y, acc.y);                         \
            acc.z = fmaf(fexp2(d[2]), aj.z, acc.z);                         \
            acc.w = fmaf(fexp2(d[3]), aj.w, acc.w);                         \
        }
        TILE(acc0, b00, b01)
        TILE(acc1, b10, b11)
        TILE(acc2, b20, b21)
        TILE(acc3, b30, b31)
#undef TILE
    }

    float s0 = (acc0.x + acc0.y) + (acc0.z + acc0.w);
    float s1 = (acc1.x + acc1.y) + (acc1.z + acc1.w);
    float s2 = (acc2.x + acc2.y) + (acc2.z + acc2.w);
    float s3 = (acc3.x + acc3.y) + (acc3.z + acc3.w);
    s0 += __shfl_xor(s0, 16); s0 += __shfl_xor(s0, 32);
    s1 += __shfl_xor(s1, 16); s1 += __shfl_xor(s1, 32);
    s2 += __shfl_xor(s2, 16); s2 += __shfl_xor(s2, 32);
    s3 += __shfl_xor(s3, 16); s3 += __shfl_xor(s3, 32);
    if (lane < 16) {                                 // apply exp2(-si2) once
        atomicAdd(&out[iBase      + lane], s0 * e0);
        atomicAdd(&out[iBase + 16 + lane], s1 * e1);
        atomicAdd(&out[iBase + 32 + lane], s2 * e2);
        atomicAdd(&out[iBase + 48 + lane], s3 * e3);
    }
}

// ---------------- launch ----------------
extern "C" void kernel_launch(void* const* d_in, const int* in_sizes, int n_in,
                              void* d_out, int out_size, void* d_ws, size_t ws_size,
                              hipStream_t stream) {
    const float* F     = (const float*)d_in[0];
    const float* alpha = (const float*)d_in[1];
    const float* bias  = (const float*)d_in[2];
    float* out = (float*)d_out;

    u16x8* Ft  = (u16x8*)d_ws;                                   // 512 KB scaled bf16
    float* sq2 = (float*)((char*)d_ws + (size_t)NN * DD * 2);    // 16 KB si2
    float* ajp = sq2 + NN;                                       // 16 KB alpha*exp2(-sj2)

    svr_prep<<<dim3(NN * DD / 8 / 256), dim3(256), 0, stream>>>(F, alpha, bias, Ft, sq2, ajp, out);
    svr_mfma4<<<dim3(16, NPY), dim3(256), 0, stream>>>((const bf16x8*)Ft, ajp, sq2, out);
}